// Round 1
// baseline (994.837 us; speedup 1.0000x reference)
//
#include <hip/hip_runtime.h>

#define NN 100000
#define NE 1600000
#define BN_EPS 1e-5f

__constant__ float c_wtab[26] = {0.7f,0.9f,0.7f,0.9f,0.3f,0.7f,0.3f,0.9f,0.3f,0.3f,0.9f,0.7f,0.1f,
                                 0.9f,0.5f,0.9f,0.5f,0.5f,0.1f,0.3f,0.7f,0.9f,0.9f,0.9f,0.9f,0.9f};

// ---------------- degree histograms ----------------
__global__ void k_hist(const int* __restrict__ src, const int* __restrict__ dst,
                       unsigned* __restrict__ dego, unsigned* __restrict__ degi){
    int e = blockIdx.x*blockDim.x + threadIdx.x;
    if (e < NE){
        atomicAdd(&dego[src[e]], 1u);
        atomicAdd(&degi[dst[e]], 1u);
    }
}

// ---------------- per-node: norms + argmax weight ----------------
__global__ void k_node(const float* __restrict__ h, const unsigned* __restrict__ dego,
                       const unsigned* __restrict__ degi, float* __restrict__ nsrc,
                       float* __restrict__ ndst, float* __restrict__ outw){
    int i = blockIdx.x*blockDim.x + threadIdx.x;
    if (i < NN){
        float d0 = (float)dego[i]; d0 = d0 < 1.f ? 1.f : d0;
        float d1 = (float)degi[i]; d1 = d1 < 1.f ? 1.f : d1;
        nsrc[i] = rsqrtf(d0);
        ndst[i] = rsqrtf(d1);
        const float* row = h + (size_t)i*26;
        float best = row[0]; int bi = 0;
        #pragma unroll
        for (int c = 1; c < 26; ++c){ float v = row[c]; if (v > best){ best = v; bi = c; } }
        outw[i] = c_wtab[bi];
    }
}

// ---------------- xn0 = h * norm_src (packed [N,26]) ----------------
__global__ void k_scale_h(const float* __restrict__ h, const float* __restrict__ nsrc,
                          float* __restrict__ xn){
    int i = blockIdx.x*blockDim.x + threadIdx.x;
    if (i < NN*26){
        int node = i / 26;
        xn[i] = h[i] * nsrc[node];
    }
}

// ---------------- prefix-sum of deg_in -> CSR offsets ----------------
__global__ void k_scan1(const unsigned* __restrict__ deg, unsigned* __restrict__ bsums){
    __shared__ unsigned s[512];
    int i = blockIdx.x*512 + threadIdx.x;
    s[threadIdx.x] = (i < NN) ? deg[i] : 0u;
    __syncthreads();
    for (int o = 256; o > 0; o >>= 1){
        if (threadIdx.x < o) s[threadIdx.x] += s[threadIdx.x + o];
        __syncthreads();
    }
    if (threadIdx.x == 0) bsums[blockIdx.x] = s[0];
}

__global__ void k_scan2(unsigned* __restrict__ bsums, unsigned* __restrict__ offsets, int nb){
    __shared__ unsigned s[512];
    int t = threadIdx.x;
    unsigned v = (t < nb) ? bsums[t] : 0u;
    s[t] = v; __syncthreads();
    for (int o = 1; o < 512; o <<= 1){
        unsigned x = (t >= o) ? s[t - o] : 0u;
        __syncthreads();
        s[t] += x;
        __syncthreads();
    }
    if (t < nb) bsums[t] = s[t] - v;   // exclusive
    if (t == 0) offsets[NN] = (unsigned)NE;
}

__global__ void k_scan3(const unsigned* __restrict__ deg, const unsigned* __restrict__ bsums,
                        unsigned* __restrict__ offsets, unsigned* __restrict__ cursor){
    __shared__ unsigned s[512];
    int i = blockIdx.x*512 + threadIdx.x;
    unsigned v = (i < NN) ? deg[i] : 0u;
    s[threadIdx.x] = v; __syncthreads();
    for (int o = 1; o < 512; o <<= 1){
        unsigned x = (threadIdx.x >= o) ? s[threadIdx.x - o] : 0u;
        __syncthreads();
        s[threadIdx.x] += x;
        __syncthreads();
    }
    if (i < NN){
        unsigned e = bsums[blockIdx.x] + s[threadIdx.x] - v;  // exclusive prefix
        offsets[i] = e;
        cursor[i]  = e;
    }
}

// ---------------- CSR fill: edges sorted by dst, storing src ----------------
__global__ void k_fill(const int* __restrict__ src, const int* __restrict__ dst,
                       unsigned* __restrict__ cursor, int* __restrict__ csr){
    int e = blockIdx.x*blockDim.x + threadIdx.x;
    if (e < NE){
        unsigned p = atomicAdd(&cursor[dst[e]], 1u);
        csr[p] = src[e];
    }
}

// ---------------- aggregation: agg[d,:] = sum over in-edges of xn[src,:] ----------------
template<int C>
__global__ void k_aggregate(const float* __restrict__ xn, const unsigned* __restrict__ offs,
                            const int* __restrict__ csr, float* __restrict__ agg){
    int node = blockIdx.x;
    int c = threadIdx.x;
    unsigned beg = offs[node], end = offs[node + 1];
    float acc = 0.f;
    unsigned e = beg;
    for (; e + 4 <= end; e += 4){
        int s0 = csr[e+0], s1 = csr[e+1], s2 = csr[e+2], s3 = csr[e+3];
        if (c < C){
            float a0 = xn[(size_t)s0*C + c];
            float a1 = xn[(size_t)s1*C + c];
            float a2 = xn[(size_t)s2*C + c];
            float a3 = xn[(size_t)s3*C + c];
            acc += (a0 + a1) + (a2 + a3);
        }
    }
    for (; e < end; ++e){
        int s0 = csr[e];
        if (c < C) acc += xn[(size_t)s0*C + c];
    }
    if (c < C) agg[(size_t)node*C + c] = acc;
}

// ---------------- GEMM: Z = A @ W (*ndst) + bias ----------------
template<int CIN, int COUT>
__global__ __launch_bounds__(256) void k_gemm(const float* __restrict__ A,
                                              const float* __restrict__ W,
                                              const float* __restrict__ bias,
                                              const float* __restrict__ ndst,
                                              float* __restrict__ Z){
    constexpr int ROWS = 64;
    constexpr int KC = 32;
    constexpr int CG = COUT / 8;          // col groups of 8
    constexpr int TPB = 256;
    constexpr int RPT = ROWS * CG / TPB;  // rows per thread
    __shared__ float sW[KC][COUT];
    __shared__ float sA[ROWS][KC + 1];
    const int tid = threadIdx.x;
    const int cg  = tid % CG;
    const int rg  = tid / CG;
    const int row0 = blockIdx.x * ROWS;
    float acc[RPT][8];
    #pragma unroll
    for (int r = 0; r < RPT; ++r)
        #pragma unroll
        for (int c = 0; c < 8; ++c) acc[r][c] = 0.f;

    for (int k0 = 0; k0 < CIN; k0 += KC){
        const int kc = (CIN - k0) < KC ? (CIN - k0) : KC;
        for (int idx = tid; idx < kc*COUT; idx += TPB){
            int kk = idx / COUT, c = idx - kk*COUT;
            sW[kk][c] = W[(k0 + kk)*COUT + c];
        }
        for (int idx = tid; idx < ROWS*kc; idx += TPB){
            int r = idx / kc, kk = idx - r*kc;
            int gr = row0 + r;
            sA[r][kk] = (gr < NN) ? A[(size_t)gr*CIN + k0 + kk] : 0.f;
        }
        __syncthreads();
        for (int kk = 0; kk < kc; ++kk){
            float w[8];
            #pragma unroll
            for (int c = 0; c < 8; ++c) w[c] = sW[kk][cg*8 + c];
            #pragma unroll
            for (int r = 0; r < RPT; ++r){
                float a = sA[rg*RPT + r][kk];
                #pragma unroll
                for (int c = 0; c < 8; ++c) acc[r][c] += a * w[c];
            }
        }
        __syncthreads();
    }
    #pragma unroll
    for (int r = 0; r < RPT; ++r){
        int gr = row0 + rg*RPT + r;
        if (gr < NN){
            float nm = ndst ? ndst[gr] : 1.f;
            float4 v0, v1;
            v0.x = acc[r][0]*nm + bias[cg*8+0];
            v0.y = acc[r][1]*nm + bias[cg*8+1];
            v0.z = acc[r][2]*nm + bias[cg*8+2];
            v0.w = acc[r][3]*nm + bias[cg*8+3];
            v1.x = acc[r][4]*nm + bias[cg*8+4];
            v1.y = acc[r][5]*nm + bias[cg*8+5];
            v1.z = acc[r][6]*nm + bias[cg*8+6];
            v1.w = acc[r][7]*nm + bias[cg*8+7];
            float* zp = &Z[(size_t)gr*COUT + cg*8];
            reinterpret_cast<float4*>(zp)[0] = v0;
            reinterpret_cast<float4*>(zp)[1] = v1;
        }
    }
}

// ---------------- BN column stats (sum, sumsq) ----------------
__global__ void k_bnstats(const float* __restrict__ Z, float* __restrict__ stats){
    float s = 0.f, sq = 0.f;
    const int total = NN * 128;
    for (int idx = blockIdx.x*256 + threadIdx.x; idx < total; idx += gridDim.x*256){
        float v = Z[idx];
        s += v; sq += v*v;
    }
    __shared__ float ls[256], lq[256];
    ls[threadIdx.x] = s; lq[threadIdx.x] = sq;
    __syncthreads();
    if (threadIdx.x < 128){
        s  = ls[threadIdx.x] + ls[threadIdx.x + 128];
        sq = lq[threadIdx.x] + lq[threadIdx.x + 128];
        atomicAdd(&stats[threadIdx.x], s);
        atomicAdd(&stats[128 + threadIdx.x], sq);
    }
}

// ---------------- BN finalize: scale/shift ----------------
__global__ void k_bnfin(float* __restrict__ stats, const float* __restrict__ g,
                        const float* __restrict__ bt){
    int c = threadIdx.x;  // 128
    float mu  = stats[c] / (float)NN;
    float var = stats[128 + c] / (float)NN - mu*mu;
    if (var < 0.f) var = 0.f;
    float sc = g[c] * rsqrtf(var + BN_EPS);
    stats[256 + c] = sc;
    stats[384 + c] = bt[c] - mu*sc;
}

// ---------------- BN apply + ReLU (+ optional *norm_src), in place ----------------
__global__ void k_bnapply(float* __restrict__ X, const float* __restrict__ stats,
                          const float* __restrict__ nsrc){
    int idx = blockIdx.x*blockDim.x + threadIdx.x;
    const int total = NN * 128;
    if (idx < total){
        int c = idx & 127;
        int node = idx >> 7;
        float v = X[idx]*stats[256 + c] + stats[384 + c];
        v = v > 0.f ? v : 0.f;
        if (nsrc) v *= nsrc[node];
        X[idx] = v;
    }
}

extern "C" void kernel_launch(void* const* d_in, const int* in_sizes, int n_in,
                              void* d_out, int out_size, void* d_ws, size_t ws_size,
                              hipStream_t stream) {
    const float* h   = (const float*)d_in[0];
    const int*   src = (const int*)d_in[1];
    const int*   dst = (const int*)d_in[2];
    const float* w0  = (const float*)d_in[3];
    const float* b0  = (const float*)d_in[4];
    const float* w1  = (const float*)d_in[5];
    const float* b1  = (const float*)d_in[6];
    const float* w2  = (const float*)d_in[7];
    const float* b2  = (const float*)d_in[8];
    const float* g0  = (const float*)d_in[9];
    const float* bt0 = (const float*)d_in[10];
    const float* g1  = (const float*)d_in[11];
    const float* bt1 = (const float*)d_in[12];
    const float* g2  = (const float*)d_in[13];
    const float* bt2 = (const float*)d_in[14];
    const float* wfc = (const float*)d_in[15];
    const float* bfc = (const float*)d_in[16];

    float* out   = (float*)d_out;                     // [NN,64]
    float* out_w = out + (size_t)NN*64;               // [NN,1]

    char* ws = (char*)d_ws;
    size_t off = 0;
    auto alloc = [&](size_t b){ size_t p = off; off += (b + 255) & ~(size_t)255; return ws + p; };

    unsigned* dego    = (unsigned*)alloc((size_t)NN*4);
    unsigned* degi    = (unsigned*)alloc((size_t)NN*4);
    float*    nsrc    = (float*)   alloc((size_t)NN*4);
    float*    ndst    = (float*)   alloc((size_t)NN*4);
    unsigned* offsets = (unsigned*)alloc((size_t)(NN+1)*4);
    unsigned* cursor  = (unsigned*)alloc((size_t)NN*4);
    unsigned* bsums   = (unsigned*)alloc(512*4);
    int*      csr     = (int*)     alloc((size_t)NE*4);
    float*    stats   = (float*)   alloc(3*512*4);    // per layer: [sum128|sumsq128|scale128|shift128]
    float*    bufA    = (float*)   alloc((size_t)NN*128*4);
    float*    bufB    = (float*)   alloc((size_t)NN*128*4);
    (void)ws_size; (void)in_sizes; (void)n_in; (void)out_size;

    hipMemsetAsync(dego, 0, (size_t)NN*4, stream);
    hipMemsetAsync(degi, 0, (size_t)NN*4, stream);
    hipMemsetAsync(stats, 0, 3*512*4, stream);

    const int NB = (NN + 511) / 512;  // 196 scan blocks

    k_hist<<<(NE + 255)/256, 256, 0, stream>>>(src, dst, dego, degi);
    k_node<<<(NN + 255)/256, 256, 0, stream>>>(h, dego, degi, nsrc, ndst, out_w);
    k_scale_h<<<(NN*26 + 255)/256, 256, 0, stream>>>(h, nsrc, bufA);
    k_scan1<<<NB, 512, 0, stream>>>(degi, bsums);
    k_scan2<<<1, 512, 0, stream>>>(bsums, offsets, NB);
    k_scan3<<<NB, 512, 0, stream>>>(degi, bsums, offsets, cursor);
    k_fill<<<(NE + 255)/256, 256, 0, stream>>>(src, dst, cursor, csr);

    // ---- layer 0: agg26 -> gemm 26x128 -> BN -> relu (*nsrc) ----
    k_aggregate<26><<<NN, 64, 0, stream>>>(bufA, offsets, csr, bufB);
    k_gemm<26,128><<<(NN + 63)/64, 256, 0, stream>>>(bufB, w0, b0, ndst, bufA);
    k_bnstats<<<1024, 256, 0, stream>>>(bufA, stats + 0*512);
    k_bnfin<<<1, 128, 0, stream>>>(stats + 0*512, g0, bt0);
    k_bnapply<<<(NN*128 + 255)/256, 256, 0, stream>>>(bufA, stats + 0*512, nsrc);

    // ---- layer 1 ----
    k_aggregate<128><<<NN, 128, 0, stream>>>(bufA, offsets, csr, bufB);
    k_gemm<128,128><<<(NN + 63)/64, 256, 0, stream>>>(bufB, w1, b1, ndst, bufA);
    k_bnstats<<<1024, 256, 0, stream>>>(bufA, stats + 1*512);
    k_bnfin<<<1, 128, 0, stream>>>(stats + 1*512, g1, bt1);
    k_bnapply<<<(NN*128 + 255)/256, 256, 0, stream>>>(bufA, stats + 1*512, nsrc);

    // ---- layer 2 (no nsrc after: feeds FC) ----
    k_aggregate<128><<<NN, 128, 0, stream>>>(bufA, offsets, csr, bufB);
    k_gemm<128,128><<<(NN + 63)/64, 256, 0, stream>>>(bufB, w2, b2, ndst, bufA);
    k_bnstats<<<1024, 256, 0, stream>>>(bufA, stats + 2*512);
    k_bnfin<<<1, 128, 0, stream>>>(stats + 2*512, g2, bt2);
    k_bnapply<<<(NN*128 + 255)/256, 256, 0, stream>>>(bufA, stats + 2*512, nullptr);

    // ---- FC: out = x @ wfc + bfc ----
    k_gemm<128,64><<<(NN + 63)/64, 256, 0, stream>>>(bufA, wfc, bfc, nullptr, out);
}

// Round 2
// 928.382 us; speedup vs baseline: 1.0716x; 1.0716x over previous
//
#include <hip/hip_runtime.h>

#define NN 100000
#define NE 1600000
#define BN_EPS 1e-5f
#define BSHIFT 5
#define NBK ((NN + 31) >> BSHIFT)   // 3125 buckets of 32 nodes

__constant__ float c_wtab[26] = {0.7f,0.9f,0.7f,0.9f,0.3f,0.7f,0.3f,0.9f,0.3f,0.3f,0.9f,0.7f,0.1f,
                                 0.9f,0.5f,0.9f,0.5f,0.5f,0.1f,0.3f,0.7f,0.9f,0.9f,0.9f,0.9f,0.9f};

__device__ __forceinline__ unsigned f2bf(float f){
    unsigned u = __float_as_uint(f);
    return (u + 0x7fffu + ((u >> 16) & 1u)) >> 16;   // round-to-nearest-even
}
__device__ __forceinline__ float bflo(unsigned v){ return __uint_as_float(v << 16); }
__device__ __forceinline__ float bfhi(unsigned v){ return __uint_as_float(v & 0xffff0000u); }

// ---------------- degree histograms ----------------
__global__ void k_hist(const int* __restrict__ src, const int* __restrict__ dst,
                       unsigned* __restrict__ dego, unsigned* __restrict__ degi){
    int e = blockIdx.x*blockDim.x + threadIdx.x;
    if (e < NE){
        atomicAdd(&dego[src[e]], 1u);
        atomicAdd(&degi[dst[e]], 1u);
    }
}

// ---------------- per-node: norms + argmax weight ----------------
__global__ void k_node(const float* __restrict__ h, const unsigned* __restrict__ dego,
                       const unsigned* __restrict__ degi, float* __restrict__ nsrc,
                       float* __restrict__ ndst, float* __restrict__ outw){
    int i = blockIdx.x*blockDim.x + threadIdx.x;
    if (i < NN){
        float d0 = (float)dego[i]; d0 = d0 < 1.f ? 1.f : d0;
        float d1 = (float)degi[i]; d1 = d1 < 1.f ? 1.f : d1;
        nsrc[i] = rsqrtf(d0);
        ndst[i] = rsqrtf(d1);
        const float* row = h + (size_t)i*26;
        float best = row[0]; int bi = 0;
        #pragma unroll
        for (int c = 1; c < 26; ++c){ float v = row[c]; if (v > best){ best = v; bi = c; } }
        outw[i] = c_wtab[bi];
    }
}

// ---------------- xn0 = h * norm_src (packed [N,26] fp32) ----------------
__global__ void k_scale_h(const float* __restrict__ h, const float* __restrict__ nsrc,
                          float* __restrict__ xn){
    int i = blockIdx.x*blockDim.x + threadIdx.x;
    if (i < NN*26){
        int node = i / 26;
        xn[i] = h[i] * nsrc[node];
    }
}

// ---------------- prefix-sum of deg_in -> CSR offsets ----------------
__global__ void k_scan1(const unsigned* __restrict__ deg, unsigned* __restrict__ bsums){
    __shared__ unsigned s[512];
    int i = blockIdx.x*512 + threadIdx.x;
    s[threadIdx.x] = (i < NN) ? deg[i] : 0u;
    __syncthreads();
    for (int o = 256; o > 0; o >>= 1){
        if (threadIdx.x < o) s[threadIdx.x] += s[threadIdx.x + o];
        __syncthreads();
    }
    if (threadIdx.x == 0) bsums[blockIdx.x] = s[0];
}

__global__ void k_scan2(unsigned* __restrict__ bsums, unsigned* __restrict__ offsets, int nb){
    __shared__ unsigned s[512];
    int t = threadIdx.x;
    unsigned v = (t < nb) ? bsums[t] : 0u;
    s[t] = v; __syncthreads();
    for (int o = 1; o < 512; o <<= 1){
        unsigned x = (t >= o) ? s[t - o] : 0u;
        __syncthreads();
        s[t] += x;
        __syncthreads();
    }
    if (t < nb) bsums[t] = s[t] - v;   // exclusive
    if (t == 0) offsets[NN] = (unsigned)NE;
}

__global__ void k_scan3(const unsigned* __restrict__ deg, const unsigned* __restrict__ bsums,
                        unsigned* __restrict__ offsets, unsigned* __restrict__ cursor){
    __shared__ unsigned s[512];
    int i = blockIdx.x*512 + threadIdx.x;
    unsigned v = (i < NN) ? deg[i] : 0u;
    s[threadIdx.x] = v; __syncthreads();
    for (int o = 1; o < 512; o <<= 1){
        unsigned x = (threadIdx.x >= o) ? s[threadIdx.x - o] : 0u;
        __syncthreads();
        s[threadIdx.x] += x;
        __syncthreads();
    }
    if (i < NN){
        unsigned e = bsums[blockIdx.x] + s[threadIdx.x] - v;  // exclusive prefix
        offsets[i] = e;
        cursor[i]  = e;
    }
}

// ---------------- bucket cursors from node offsets ----------------
__global__ void k_bcur_init(const unsigned* __restrict__ offsets, unsigned* __restrict__ bcur){
    int b = blockIdx.x*256 + threadIdx.x;
    if (b < NBK) bcur[b] = offsets[b << BSHIFT];
}

// ---------------- pass 1: scatter (dst,src) pairs into coarse buckets ----------------
__global__ void k_bucket(const int* __restrict__ src, const int* __restrict__ dst,
                         unsigned* __restrict__ bcur, uint2* __restrict__ pairs){
    int e = blockIdx.x*blockDim.x + threadIdx.x;
    if (e < NE){
        int d = dst[e];
        unsigned p = atomicAdd(&bcur[d >> BSHIFT], 1u);
        pairs[p] = make_uint2((unsigned)d, (unsigned)src[e]);
    }
}

// ---------------- pass 2: within-bucket scatter to exact CSR position ----------------
__global__ void k_fill2(const unsigned* __restrict__ offsets, const uint2* __restrict__ pairs,
                        unsigned* __restrict__ cursor, int* __restrict__ csr){
    int b = blockIdx.x;
    unsigned beg = offsets[b << BSHIFT];
    int hi = (b + 1) << BSHIFT; if (hi > NN) hi = NN;
    unsigned end = offsets[hi];
    for (unsigned e = beg + threadIdx.x; e < end; e += blockDim.x){
        uint2 pr = pairs[e];
        unsigned p = atomicAdd(&cursor[pr.x], 1u);
        csr[p] = (int)pr.y;
    }
}

// ---------------- fp32 aggregation (layer 0, C=26) ----------------
template<int C>
__global__ void k_aggregate(const float* __restrict__ xn, const unsigned* __restrict__ offs,
                            const int* __restrict__ csr, float* __restrict__ agg){
    int node = blockIdx.x;
    int c = threadIdx.x;
    unsigned beg = offs[node], end = offs[node + 1];
    float acc = 0.f;
    unsigned e = beg;
    for (; e + 4 <= end; e += 4){
        int s0 = csr[e+0], s1 = csr[e+1], s2 = csr[e+2], s3 = csr[e+3];
        if (c < C){
            float a0 = xn[(size_t)s0*C + c];
            float a1 = xn[(size_t)s1*C + c];
            float a2 = xn[(size_t)s2*C + c];
            float a3 = xn[(size_t)s3*C + c];
            acc += (a0 + a1) + (a2 + a3);
        }
    }
    for (; e < end; ++e){
        int s0 = csr[e];
        if (c < C) acc += xn[(size_t)s0*C + c];
    }
    if (c < C) agg[(size_t)node*C + c] = acc;
}

// ---------------- bf16 aggregation (layers 1/2, C=128 as 64 dwords) ----------------
__global__ void k_agg_bf(const unsigned* __restrict__ xn, const unsigned* __restrict__ offs,
                         const int* __restrict__ csr, float* __restrict__ agg){
    int node = blockIdx.x;
    int t = threadIdx.x;   // 64 threads, each owns 2 channels
    unsigned beg = offs[node], end = offs[node + 1];
    float a0 = 0.f, a1 = 0.f;
    unsigned e = beg;
    for (; e + 4 <= end; e += 4){
        int s0 = csr[e+0], s1 = csr[e+1], s2 = csr[e+2], s3 = csr[e+3];
        unsigned v0 = xn[(size_t)s0*64 + t];
        unsigned v1 = xn[(size_t)s1*64 + t];
        unsigned v2 = xn[(size_t)s2*64 + t];
        unsigned v3 = xn[(size_t)s3*64 + t];
        a0 += (bflo(v0) + bflo(v1)) + (bflo(v2) + bflo(v3));
        a1 += (bfhi(v0) + bfhi(v1)) + (bfhi(v2) + bfhi(v3));
    }
    for (; e < end; ++e){
        int s0 = csr[e];
        unsigned v0 = xn[(size_t)s0*64 + t];
        a0 += bflo(v0);
        a1 += bfhi(v0);
    }
    reinterpret_cast<float2*>(agg + (size_t)node*128)[t] = make_float2(a0, a1);
}

// ---------------- GEMM: Z = A @ W (*ndst) + bias ----------------
template<int CIN, int COUT>
__global__ __launch_bounds__(256) void k_gemm(const float* __restrict__ A,
                                              const float* __restrict__ W,
                                              const float* __restrict__ bias,
                                              const float* __restrict__ ndst,
                                              float* __restrict__ Z){
    constexpr int ROWS = 64;
    constexpr int KC = 32;
    constexpr int CG = COUT / 8;          // col groups of 8
    constexpr int TPB = 256;
    constexpr int RPT = ROWS * CG / TPB;  // rows per thread
    __shared__ float sW[KC][COUT];
    __shared__ float sA[ROWS][KC + 1];
    const int tid = threadIdx.x;
    const int cg  = tid % CG;
    const int rg  = tid / CG;
    const int row0 = blockIdx.x * ROWS;
    float acc[RPT][8];
    #pragma unroll
    for (int r = 0; r < RPT; ++r)
        #pragma unroll
        for (int c = 0; c < 8; ++c) acc[r][c] = 0.f;

    for (int k0 = 0; k0 < CIN; k0 += KC){
        const int kc = (CIN - k0) < KC ? (CIN - k0) : KC;
        for (int idx = tid; idx < kc*COUT; idx += TPB){
            int kk = idx / COUT, c = idx - kk*COUT;
            sW[kk][c] = W[(k0 + kk)*COUT + c];
        }
        for (int idx = tid; idx < ROWS*kc; idx += TPB){
            int r = idx / kc, kk = idx - r*kc;
            int gr = row0 + r;
            sA[r][kk] = (gr < NN) ? A[(size_t)gr*CIN + k0 + kk] : 0.f;
        }
        __syncthreads();
        for (int kk = 0; kk < kc; ++kk){
            float w[8];
            #pragma unroll
            for (int c = 0; c < 8; ++c) w[c] = sW[kk][cg*8 + c];
            #pragma unroll
            for (int r = 0; r < RPT; ++r){
                float a = sA[rg*RPT + r][kk];
                #pragma unroll
                for (int c = 0; c < 8; ++c) acc[r][c] += a * w[c];
            }
        }
        __syncthreads();
    }
    #pragma unroll
    for (int r = 0; r < RPT; ++r){
        int gr = row0 + rg*RPT + r;
        if (gr < NN){
            float nm = ndst ? ndst[gr] : 1.f;
            float4 v0, v1;
            v0.x = acc[r][0]*nm + bias[cg*8+0];
            v0.y = acc[r][1]*nm + bias[cg*8+1];
            v0.z = acc[r][2]*nm + bias[cg*8+2];
            v0.w = acc[r][3]*nm + bias[cg*8+3];
            v1.x = acc[r][4]*nm + bias[cg*8+4];
            v1.y = acc[r][5]*nm + bias[cg*8+5];
            v1.z = acc[r][6]*nm + bias[cg*8+6];
            v1.w = acc[r][7]*nm + bias[cg*8+7];
            float* zp = &Z[(size_t)gr*COUT + cg*8];
            reinterpret_cast<float4*>(zp)[0] = v0;
            reinterpret_cast<float4*>(zp)[1] = v1;
        }
    }
}

// ---------------- BN column stats (sum, sumsq) ----------------
__global__ void k_bnstats(const float* __restrict__ Z, float* __restrict__ stats){
    float s = 0.f, sq = 0.f;
    const int total = NN * 128;
    for (int idx = blockIdx.x*256 + threadIdx.x; idx < total; idx += gridDim.x*256){
        float v = Z[idx];
        s += v; sq += v*v;
    }
    __shared__ float ls[256], lq[256];
    ls[threadIdx.x] = s; lq[threadIdx.x] = sq;
    __syncthreads();
    if (threadIdx.x < 128){
        s  = ls[threadIdx.x] + ls[threadIdx.x + 128];
        sq = lq[threadIdx.x] + lq[threadIdx.x + 128];
        atomicAdd(&stats[threadIdx.x], s);
        atomicAdd(&stats[128 + threadIdx.x], sq);
    }
}

// ---------------- BN finalize: scale/shift ----------------
__global__ void k_bnfin(float* __restrict__ stats, const float* __restrict__ g,
                        const float* __restrict__ bt){
    int c = threadIdx.x;  // 128
    float mu  = stats[c] / (float)NN;
    float var = stats[128 + c] / (float)NN - mu*mu;
    if (var < 0.f) var = 0.f;
    float sc = g[c] * rsqrtf(var + BN_EPS);
    stats[256 + c] = sc;
    stats[384 + c] = bt[c] - mu*sc;
}

// ---------------- BN apply + ReLU + *nsrc -> bf16 packed [N,64] dwords ----------------
__global__ void k_bnapply_bf(const float* __restrict__ X, const float* __restrict__ stats,
                             const float* __restrict__ nsrc, unsigned* __restrict__ out){
    int idx = blockIdx.x*blockDim.x + threadIdx.x;
    if (idx < NN*64){
        int d = idx & 63;
        int node = idx >> 6;
        int c0 = d << 1;
        float2 x = reinterpret_cast<const float2*>(X)[idx];
        float ns = nsrc[node];
        float v0 = x.x*stats[256 + c0]     + stats[384 + c0];
        float v1 = x.y*stats[256 + c0 + 1] + stats[384 + c0 + 1];
        v0 = v0 > 0.f ? v0*ns : 0.f;
        v1 = v1 > 0.f ? v1*ns : 0.f;
        out[idx] = f2bf(v0) | (f2bf(v1) << 16);
    }
}

// ---------------- BN apply + ReLU, fp32 in place (layer 2) ----------------
__global__ void k_bnapply_f32(float* __restrict__ X, const float* __restrict__ stats){
    int idx = blockIdx.x*blockDim.x + threadIdx.x;
    const int total = NN * 128;
    if (idx < total){
        int c = idx & 127;
        float v = X[idx]*stats[256 + c] + stats[384 + c];
        X[idx] = v > 0.f ? v : 0.f;
    }
}

extern "C" void kernel_launch(void* const* d_in, const int* in_sizes, int n_in,
                              void* d_out, int out_size, void* d_ws, size_t ws_size,
                              hipStream_t stream) {
    const float* h   = (const float*)d_in[0];
    const int*   src = (const int*)d_in[1];
    const int*   dst = (const int*)d_in[2];
    const float* w0  = (const float*)d_in[3];
    const float* b0  = (const float*)d_in[4];
    const float* w1  = (const float*)d_in[5];
    const float* b1  = (const float*)d_in[6];
    const float* w2  = (const float*)d_in[7];
    const float* b2  = (const float*)d_in[8];
    const float* g0  = (const float*)d_in[9];
    const float* bt0 = (const float*)d_in[10];
    const float* g1  = (const float*)d_in[11];
    const float* bt1 = (const float*)d_in[12];
    const float* g2  = (const float*)d_in[13];
    const float* bt2 = (const float*)d_in[14];
    const float* wfc = (const float*)d_in[15];
    const float* bfc = (const float*)d_in[16];

    float* out   = (float*)d_out;                     // [NN,64]
    float* out_w = out + (size_t)NN*64;               // [NN,1]

    char* ws = (char*)d_ws;
    size_t off = 0;
    auto alloc = [&](size_t b){ size_t p = off; off += (b + 255) & ~(size_t)255; return ws + p; };

    unsigned* dego    = (unsigned*)alloc((size_t)NN*4);
    unsigned* degi    = (unsigned*)alloc((size_t)NN*4);
    float*    nsrc    = (float*)   alloc((size_t)NN*4);
    float*    ndst    = (float*)   alloc((size_t)NN*4);
    unsigned* offsets = (unsigned*)alloc((size_t)(NN+1)*4);
    unsigned* cursor  = (unsigned*)alloc((size_t)NN*4);
    unsigned* bsums   = (unsigned*)alloc(512*4);
    unsigned* bcur    = (unsigned*)alloc((size_t)NBK*4);
    int*      csr     = (int*)     alloc((size_t)NE*4);
    float*    stats   = (float*)   alloc(3*512*4);    // per layer: [sum|sumsq|scale|shift] x128
    float*    bufA    = (float*)   alloc((size_t)NN*128*4);   // fp32 GEMM out
    float*    bufB    = (float*)   alloc((size_t)NN*128*4);   // fp32 agg out (aliases pairs early)
    unsigned* bufC    = (unsigned*)alloc((size_t)NN*64*4);    // bf16 features / fp32 xn0
    (void)ws_size; (void)in_sizes; (void)n_in; (void)out_size;

    uint2* pairs = (uint2*)bufB;   // 12.8 MB, consumed before bufB's first real write

    hipMemsetAsync(dego, 0, (size_t)NN*4, stream);
    hipMemsetAsync(degi, 0, (size_t)NN*4, stream);
    hipMemsetAsync(stats, 0, 3*512*4, stream);

    const int NB = (NN + 511) / 512;  // scan blocks

    k_hist<<<(NE + 255)/256, 256, 0, stream>>>(src, dst, dego, degi);
    k_node<<<(NN + 255)/256, 256, 0, stream>>>(h, dego, degi, nsrc, ndst, out_w);
    k_scale_h<<<(NN*26 + 255)/256, 256, 0, stream>>>(h, nsrc, (float*)bufC);
    k_scan1<<<NB, 512, 0, stream>>>(degi, bsums);
    k_scan2<<<1, 512, 0, stream>>>(bsums, offsets, NB);
    k_scan3<<<NB, 512, 0, stream>>>(degi, bsums, offsets, cursor);
    k_bcur_init<<<(NBK + 255)/256, 256, 0, stream>>>(offsets, bcur);
    k_bucket<<<(NE + 255)/256, 256, 0, stream>>>(src, dst, bcur, pairs);
    k_fill2<<<NBK, 256, 0, stream>>>(offsets, pairs, cursor, csr);

    // ---- layer 0: agg26 -> gemm 26x128 -> BN -> relu*nsrc -> bf16 ----
    k_aggregate<26><<<NN, 64, 0, stream>>>((const float*)bufC, offsets, csr, bufB);
    k_gemm<26,128><<<(NN + 63)/64, 256, 0, stream>>>(bufB, w0, b0, ndst, bufA);
    k_bnstats<<<1024, 256, 0, stream>>>(bufA, stats + 0*512);
    k_bnfin<<<1, 128, 0, stream>>>(stats + 0*512, g0, bt0);
    k_bnapply_bf<<<(NN*64 + 255)/256, 256, 0, stream>>>(bufA, stats + 0*512, nsrc, bufC);

    // ---- layer 1 ----
    k_agg_bf<<<NN, 64, 0, stream>>>(bufC, offsets, csr, bufB);
    k_gemm<128,128><<<(NN + 63)/64, 256, 0, stream>>>(bufB, w1, b1, ndst, bufA);
    k_bnstats<<<1024, 256, 0, stream>>>(bufA, stats + 1*512);
    k_bnfin<<<1, 128, 0, stream>>>(stats + 1*512, g1, bt1);
    k_bnapply_bf<<<(NN*64 + 255)/256, 256, 0, stream>>>(bufA, stats + 1*512, nsrc, bufC);

    // ---- layer 2 ----
    k_agg_bf<<<NN, 64, 0, stream>>>(bufC, offsets, csr, bufB);
    k_gemm<128,128><<<(NN + 63)/64, 256, 0, stream>>>(bufB, w2, b2, ndst, bufA);
    k_bnstats<<<1024, 256, 0, stream>>>(bufA, stats + 2*512);
    k_bnfin<<<1, 128, 0, stream>>>(stats + 2*512, g2, bt2);
    k_bnapply_f32<<<(NN*128 + 255)/256, 256, 0, stream>>>(bufA, stats + 2*512);

    // ---- FC: out = x @ wfc + bfc ----
    k_gemm<128,64><<<(NN + 63)/64, 256, 0, stream>>>(bufA, wfc, bfc, nullptr, out);
}